// Round 3
// baseline (67470.264 us; speedup 1.0000x reference)
//
#include <hip/hip_runtime.h>
#include <stdint.h>

#define BB 64
#define TT 512
#define II 512
#define HH 1024
#define OO 512
#define KD 1536      // II + HH
#define KC 256       // k-chunk staged in LDS
#define NCH 6        // KD / KC
#define NBLK 256
#define NTHR 1024
#define NWAVE 16

// workspace layout (floats)
#define WS_ROOT 0                          // root barrier counter (padded 128B)
#define WS_GRP  32                         // 8 group counters, each padded to 32 floats
#define WS_HBUF 288                        // [2][BB][HH] h double buffer
#define WS_NFLOATS (WS_HBUF + 2 * BB * HH)

// LDS layout (floats)
#define L_COMB0 0
#define L_COMB1 (KC * BB)                  // 16384
#define L_YBUF  (2 * KC * BB)              // 32768 (16 waves * 64)
#define L_GPART (L_YBUF + NWAVE * BB)      // 33792 (16 waves * 4 gates * 64)
#define L_NFLOATS (L_GPART + NWAVE * 4 * BB)   // 37888 floats = 151552 B

__device__ __forceinline__ float sigm(float v) {
  return 1.0f / (1.0f + __expf(-v));
}
__device__ __forceinline__ float tanh_c(float v) {
  v = fminf(fmaxf(v, -20.0f), 20.0f);
  float e = __expf(-2.0f * v);
  return (1.0f - e) / (1.0f + e);
}

// Coherent (agent-scope, sc0 sc1) 8-byte load: bypasses the stale L1/L2 copy
// WITHOUT any cache-wide invalidate. This is how h crosses XCDs.
__device__ __forceinline__ float2 cohere_ld8(const float* p) {
  unsigned long long q = __hip_atomic_load((const unsigned long long*)p,
                                           __ATOMIC_RELAXED, __HIP_MEMORY_SCOPE_AGENT);
  return __builtin_bit_cast(float2, q);
}

// Tree grid barrier. NO acquire/release fences anywhere (those emit
// buffer_inv / buffer_wbl2, which round 1/2 showed evict the L2-resident
// weights every step). h visibility is via per-access sc1 ops + vmcnt(0)
// before signaling.
__device__ __forceinline__ void grid_barrier(uint32_t* grpc, uint32_t* rootc,
                                             uint32_t grp_target, uint32_t root_target) {
  asm volatile("s_waitcnt vmcnt(0)" ::: "memory");   // h stores globally visible
  __syncthreads();
  if (threadIdx.x == 0) {
    uint32_t old = __hip_atomic_fetch_add(grpc, 1u, __ATOMIC_RELAXED, __HIP_MEMORY_SCOPE_AGENT);
    if (old == grp_target - 1u)
      __hip_atomic_fetch_add(rootc, 1u, __ATOMIC_RELAXED, __HIP_MEMORY_SCOPE_AGENT);
    while (__hip_atomic_load(rootc, __ATOMIC_RELAXED, __HIP_MEMORY_SCOPE_AGENT) < root_target)
      __builtin_amdgcn_s_sleep(2);
  }
  __syncthreads();
}

__global__ void __launch_bounds__(NTHR, 4)
lstm_kernel(const float* __restrict__ x,
            const float* __restrict__ Wf, const float* __restrict__ bf,
            const float* __restrict__ Wi, const float* __restrict__ bi,
            const float* __restrict__ Wc, const float* __restrict__ bc,
            const float* __restrict__ Wo, const float* __restrict__ bo,
            const float* __restrict__ Wfc, const float* __restrict__ bfc,
            float* __restrict__ out, float* __restrict__ ws)
{
  extern __shared__ float lds[];
  const int tid  = threadIdx.x;
  const int blk  = blockIdx.x;
  const int wave = tid >> 6;
  const int lane = tid & 63;
  const int b    = lane;             // batch owned by this lane

  uint32_t* rootc = (uint32_t*)ws + WS_ROOT;
  uint32_t* grpc  = (uint32_t*)ws + WS_GRP + (blk & 7) * 32;
  float* hbuf = ws + WS_HBUF;        // [2][BB][HH]

  // gate work: wave -> (unit ul, k-quarter ks)
  const int ul = wave & 3;
  const int ks = wave >> 2;          // 0..3 : slots [ks*16, ks*16+16) per chunk
  const int u  = __builtin_amdgcn_readfirstlane(blk * 4 + ul);
  const float* rowf = Wf + (size_t)u * KD;
  const float* rowi = Wi + (size_t)u * KD;
  const float* rowc = Wc + (size_t)u * KD;
  const float* rowo = Wo + (size_t)u * KD;
  const float bsf = bf[u], bsi = bi[u], bsc = bc[u], bso = bo[u];

  // y work: wave -> (col yc, k-eighth yk); y is computed from the LDS-staged
  // h chunks (no second global h broadcast).
  const int yc = wave >> 3;          // 0/1
  const int yk = wave & 7;           // slots [yk*8, yk*8+8) per h-chunk
  const int oidx = __builtin_amdgcn_readfirstlane(blk * 2 + yc);
  const float* rowy = Wfc + (size_t)oidx * HH;

  float cstate = 0.0f;               // c[u][b] (waves 0-3)
  float hlast  = 0.0f;               // h[u][b] after the last step (waves 0-3)

  for (int it = 0; it <= TT; ++it) {
    const float* hprev = hbuf + (size_t)(it & 1) * (BB * HH);
    float*       hnext = hbuf + (size_t)((it + 1) & 1) * (BB * HH);
    const int xit = (it < TT) ? it : 0;   // keep x addresses in-bounds at it==TT

    float a0 = 0.f, a1 = 0.f, a2 = 0.f, a3 = 0.f;
    float accy = 0.f;

    // ---- prologue: stage chunk 0 (pure x) linear-src -> swizzled LDS ----
    {
      float4 v[4];
      #pragma unroll
      for (int i = 0; i < 4; ++i) {
        int bs = i * 16 + wave;
        const float* src = x + (size_t)bs * (TT * II) + (size_t)xit * II;
        v[i] = ((const float4*)src)[lane];
      }
      float4* dstb = (float4*)(lds + L_COMB0);
      #pragma unroll
      for (int i = 0; i < 4; ++i) {
        int bs = i * 16 + wave;
        dstb[bs * 64 + (lane ^ (bs & 15))] = v[i];
      }
    }
    __syncthreads();

    // ---- main K loop: double-buffered chunks ----
    for (int kc = 0; kc < NCH; ++kc) {
      float4 v[4];
      if (kc + 1 < NCH) {                    // issue next chunk's loads early
        const int k0n = (kc + 1) * KC;
        if (k0n < II) {
          #pragma unroll
          for (int i = 0; i < 4; ++i) {
            int bs = i * 16 + wave;
            const float* src = x + (size_t)bs * (TT * II) + (size_t)xit * II + k0n;
            v[i] = ((const float4*)src)[lane];
          }
        } else {
          #pragma unroll
          for (int i = 0; i < 4; ++i) {
            int bs = i * 16 + wave;
            const float* src = hprev + (size_t)bs * HH + (k0n - II) + lane * 4;
            float2 lo = cohere_ld8(src);
            float2 hi = cohere_ld8(src + 2);
            v[i] = make_float4(lo.x, lo.y, hi.x, hi.y);
          }
        }
      }

      {
        const float4* cb = (const float4*)(lds + ((kc & 1) ? L_COMB1 : L_COMB0)) + b * 64;
        const int m = b & 15;
        if (it < TT) {                        // gate partial dots (k-quarter ks)
          const int k0 = kc * KC;
          #pragma unroll 4
          for (int s = ks * 16; s < ks * 16 + 16; ++s) {
            float4 cv = cb[s ^ m];
            float4 w0 = *(const float4*)(rowf + k0 + 4 * s);
            float4 w1 = *(const float4*)(rowi + k0 + 4 * s);
            float4 w2 = *(const float4*)(rowc + k0 + 4 * s);
            float4 w3 = *(const float4*)(rowo + k0 + 4 * s);
            a0 += cv.x * w0.x + cv.y * w0.y + cv.z * w0.z + cv.w * w0.w;
            a1 += cv.x * w1.x + cv.y * w1.y + cv.z * w1.z + cv.w * w1.w;
            a2 += cv.x * w2.x + cv.y * w2.y + cv.z * w2.z + cv.w * w2.w;
            a3 += cv.x * w3.x + cv.y * w3.y + cv.z * w3.z + cv.w * w3.w;
          }
        }
        if (kc >= 2) {                        // y partial dots on h-chunks
          const int kh0 = kc * KC - II;
          #pragma unroll
          for (int j = 0; j < 8; ++j) {
            int s = yk * 8 + j;
            float4 cv = cb[s ^ m];
            float4 wv = *(const float4*)(rowy + kh0 + 4 * s);
            accy += cv.x * wv.x + cv.y * wv.y + cv.z * wv.z + cv.w * wv.w;
          }
        }
      }

      if (kc + 1 < NCH) {                    // write staged regs, swap
        float4* dstb = (float4*)(lds + (((kc + 1) & 1) ? L_COMB1 : L_COMB0));
        #pragma unroll
        for (int i = 0; i < 4; ++i) {
          int bs = i * 16 + wave;
          dstb[bs * 64 + (lane ^ (bs & 15))] = v[i];
        }
        __syncthreads();
      }
    }

    // ---- publish partials ----
    lds[L_GPART + wave * 256 + 0 * 64 + b] = a0;
    lds[L_GPART + wave * 256 + 1 * 64 + b] = a1;
    lds[L_GPART + wave * 256 + 2 * 64 + b] = a2;
    lds[L_GPART + wave * 256 + 3 * 64 + b] = a3;
    lds[L_YBUF + wave * BB + b] = accy;
    __syncthreads();

    // ---- gate combine + state update (waves 0-3) ----
    if (it < TT && wave < 4) {
      float t0 = 0.f, t1 = 0.f, t2 = 0.f, t3 = 0.f;
      #pragma unroll
      for (int q = 0; q < 4; ++q) {
        int w = q * 4 + ul;
        t0 += lds[L_GPART + w * 256 + 0 * 64 + b];
        t1 += lds[L_GPART + w * 256 + 1 * 64 + b];
        t2 += lds[L_GPART + w * 256 + 2 * 64 + b];
        t3 += lds[L_GPART + w * 256 + 3 * 64 + b];
      }
      float gf = sigm(t0 + bsf);
      float gi = sigm(t1 + bsi);
      float gc = tanh_c(t2 + bsc);
      float go = sigm(t3 + bso);
      cstate = gf * cstate + gi * gc;
      float hv = go * tanh_c(cstate);
      hlast = hv;
      // coherent store: write-through past L2 so other XCDs' sc1 reads see it
      __hip_atomic_store(&hnext[(size_t)b * HH + u], hv,
                         __ATOMIC_RELAXED, __HIP_MEMORY_SCOPE_AGENT);
    }

    // ---- y output for step it-1 (h_{it-1} was what we staged) ----
    if (it > 0 && tid < 2 * BB) {
      int q  = tid >> 6;
      int qb = tid & 63;
      float yv = bfc[blk * 2 + q];
      #pragma unroll
      for (int j = 0; j < 8; ++j)
        yv += lds[L_YBUF + (q * 8 + j) * BB + qb];
      out[(size_t)qb * (TT * OO) + (size_t)(it - 1) * OO + (blk * 2 + q)] = yv;
    }

    // ---- final h/c outputs from registers ----
    if (it == TT && wave < 4) {
      out[(size_t)(BB * TT * OO) + (size_t)b * HH + u] = hlast;
      out[(size_t)(BB * TT * OO + BB * HH) + (size_t)b * HH + u] = cstate;
    }

    if (it < TT)
      grid_barrier(grpc, rootc, 32u * (uint32_t)(it + 1), 8u * (uint32_t)(it + 1));
  }
}

extern "C" void kernel_launch(void* const* d_in, const int* in_sizes, int n_in,
                              void* d_out, int out_size, void* d_ws, size_t ws_size,
                              hipStream_t stream) {
  (void)in_sizes; (void)n_in; (void)out_size; (void)ws_size;
  const float* x   = (const float*)d_in[0];
  const float* Wf  = (const float*)d_in[1];
  const float* bf  = (const float*)d_in[2];
  const float* Wi  = (const float*)d_in[3];
  const float* bi  = (const float*)d_in[4];
  const float* Wc  = (const float*)d_in[5];
  const float* bc  = (const float*)d_in[6];
  const float* Wo  = (const float*)d_in[7];
  const float* bo  = (const float*)d_in[8];
  const float* Wfc = (const float*)d_in[9];
  const float* bfc = (const float*)d_in[10];
  float* out = (float*)d_out;
  float* ws  = (float*)d_ws;

  // zero barrier counters + h0 (deterministic per call)
  hipMemsetAsync(d_ws, 0, (size_t)WS_NFLOATS * sizeof(float), stream);

  hipFuncSetAttribute((const void*)lstm_kernel,
                      hipFuncAttributeMaxDynamicSharedMemorySize,
                      (int)(L_NFLOATS * sizeof(float)));

  void* args[] = { &x, &Wf, &bf, &Wi, &bi, &Wc, &bc, &Wo, &bo, &Wfc, &bfc, &out, &ws };
  hipLaunchCooperativeKernel(reinterpret_cast<void*>(lstm_kernel),
                             dim3(NBLK), dim3(NTHR), args,
                             (unsigned)(L_NFLOATS * sizeof(float)), stream);
}

// Round 5
// 40681.073 us; speedup vs baseline: 1.6585x; 1.6585x over previous
//
#include <hip/hip_runtime.h>
#include <stdint.h>

#define BB 64
#define TT 512
#define II 512
#define HH 1024
#define OO 512
#define KC 128            // k per LDS chunk
#define NSL 32            // float4-slots per chunk
#define NCH 12            // (II+HH)/KC ; chunks 0..3 = x, 4..11 = h
#define NBLK 256
#define NTHR 1024
#define NWAVE 16

// ws float layout
#define WS_ROOT 0
#define WS_GRP  32                        // 8 counters, 32-float padded
#define WS_HBUF 288                       // [2][BB][HH]
#define WS_WGT  (WS_HBUF + 2*BB*HH)       // f16 gate weights, 32B-aligned byte off
#define WS_CTRL_FLOATS WS_WGT             // memset region (control + hbuf)

// LDS float layout
#define L_COMB0 0                         // 8192
#define L_COMB1 (KC*BB)                   // 8192..16384
#define L_GPART (2*KC*BB)                 // 16*64*20 = 20480 (w-dim padded to 20)
#define L_YBUF  (L_GPART + 16*64*20)      // 16*2*64 = 2048
#define L_HGATH (L_YBUF + 2048)           // 256
#define L_NFLOATS (L_HGATH + 256)         // 39168 floats = 156672 B

typedef _Float16 h2 __attribute__((ext_vector_type(2)));

#if __has_builtin(__builtin_amdgcn_fdot2)
#define FDOT2(a,b,c) __builtin_amdgcn_fdot2((a),(b),(c),false)
#else
static __device__ __forceinline__ float FDOT2(h2 a, h2 b, float c) {
  return fmaf((float)a.x, (float)b.x, fmaf((float)a.y, (float)b.y, c));
}
#endif

static __device__ __forceinline__ h2 bc_h2(uint32_t v) { return __builtin_bit_cast(h2, v); }
static __device__ __forceinline__ h2 pkrtz(float a, float b) {
  return __builtin_bit_cast(h2, __builtin_amdgcn_cvt_pkrtz(a, b));
}

__device__ __forceinline__ float sigm(float v) { return 1.0f / (1.0f + __expf(-v)); }
__device__ __forceinline__ float tanh_c(float v) {
  v = fminf(fmaxf(v, -20.0f), 20.0f);
  float e = __expf(-2.0f * v);
  return (1.0f - e) / (1.0f + e);
}

// agent-scope (sc0 sc1) 8B load/store: L1/L2-bypass per-access coherence,
// NO cache-wide invalidates (those caused round 1/2's weight eviction).
__device__ __forceinline__ float2 cohere_ld8(const float* p) {
  unsigned long long q = __hip_atomic_load((const unsigned long long*)p,
                                           __ATOMIC_RELAXED, __HIP_MEMORY_SCOPE_AGENT);
  return __builtin_bit_cast(float2, q);
}
__device__ __forceinline__ void cohere_st8(float* p, float a, float b) {
  float2 v = make_float2(a, b);
  __hip_atomic_store((unsigned long long*)p, __builtin_bit_cast(unsigned long long, v),
                     __ATOMIC_RELAXED, __HIP_MEMORY_SCOPE_AGENT);
}

__device__ __forceinline__ void grid_barrier(uint32_t* grpc, uint32_t* rootc,
                                             uint32_t grp_target, uint32_t root_target) {
  asm volatile("s_waitcnt vmcnt(0)" ::: "memory");
  __syncthreads();
  if (threadIdx.x == 0) {
    uint32_t old = __hip_atomic_fetch_add(grpc, 1u, __ATOMIC_RELAXED, __HIP_MEMORY_SCOPE_AGENT);
    if (old == grp_target - 1u)
      __hip_atomic_fetch_add(rootc, 1u, __ATOMIC_RELAXED, __HIP_MEMORY_SCOPE_AGENT);
    while (__hip_atomic_load(rootc, __ATOMIC_RELAXED, __HIP_MEMORY_SCOPE_AGENT) < root_target)
      __builtin_amdgcn_s_sleep(2);
  }
  __syncthreads();
}

// -------- preprocess: fp32 gate weights -> f16, gate-interleaved --------
// layout: per (blk, sg): 8 uint4 = [u0:{f(k0..3),i(k0..3)},{c,o}], u1:..., u3
__global__ void __launch_bounds__(256) wprep(
    const float* __restrict__ Wf, const float* __restrict__ Wi,
    const float* __restrict__ Wc, const float* __restrict__ Wo,
    float* __restrict__ ws)
{
  int idx = blockIdx.x * 256 + threadIdx.x;       // blk*384 + sg
  if (idx >= NBLK * 384) return;
  int blkk = idx / 384, sg = idx % 384;
  uint4* dst = (uint4*)(ws + WS_WGT) + (size_t)idx * 8;
  const float* Ws[4] = {Wf, Wi, Wc, Wo};
  #pragma unroll
  for (int u = 0; u < 4; ++u) {
    int row = blkk * 4 + u;
    uint32_t p[8];
    #pragma unroll
    for (int g = 0; g < 4; ++g) {
      const float* src = Ws[g] + (size_t)row * 1536 + sg * 4;
      h2 lo; lo.x = (_Float16)src[0]; lo.y = (_Float16)src[1];   // RNE
      h2 hi; hi.x = (_Float16)src[2]; hi.y = (_Float16)src[3];
      p[g*2+0] = __builtin_bit_cast(uint32_t, lo);
      p[g*2+1] = __builtin_bit_cast(uint32_t, hi);
    }
    dst[u*2+0] = make_uint4(p[0], p[1], p[2], p[3]);
    dst[u*2+1] = make_uint4(p[4], p[5], p[6], p[7]);
  }
}

// -------- staging helpers --------
#define ISSUE(vv, kcn) { \
    const int koff_ = (kcn) * KC; \
    _Pragma("unroll") \
    for (int i_ = 0; i_ < 2; ++i_) { \
      const int bs_ = (tid >> 5) + i_ * 32; \
      const int sl_ = tid & 31; \
      if (koff_ < II) { \
        vv[i_] = *(const float4*)(x + (size_t)bs_ * (TT*II) + (size_t)xit * II + koff_ + sl_ * 4); \
      } else { \
        const float* sp_ = hprev + (size_t)bs_ * HH + (koff_ - II) + sl_ * 4; \
        float2 lo_ = cohere_ld8(sp_); float2 hi_ = cohere_ld8(sp_ + 2); \
        vv[i_] = make_float4(lo_.x, lo_.y, hi_.x, hi_.y); \
      } \
    } }

#define WRITE(vv, kcn) { \
    float4* dstb_ = (float4*)(lds + (((kcn) & 1) ? L_COMB1 : L_COMB0)); \
    _Pragma("unroll") \
    for (int i_ = 0; i_ < 2; ++i_) { \
      const int bs_ = (tid >> 5) + i_ * 32; \
      const int sl_ = tid & 31; \
      dstb_[bs_ * NSL + (sl_ ^ (bs_ & 15))] = vv[i_]; \
    } }

__global__ void __launch_bounds__(NTHR, 4)
lstm_kernel(const float* __restrict__ x,
            const float* __restrict__ bf, const float* __restrict__ bi,
            const float* __restrict__ bc, const float* __restrict__ bo,
            const float* __restrict__ Wfc, const float* __restrict__ bfc,
            float* __restrict__ out, float* __restrict__ ws)
{
  extern __shared__ float lds[];
  const int tid  = threadIdx.x;
  const int blk  = blockIdx.x;
  const int wave = tid >> 6;
  const int lane = tid & 63;
  const int b    = lane;
  const int mm   = b & 15;

  uint32_t* rootc = (uint32_t*)ws + WS_ROOT;
  uint32_t* grpc  = (uint32_t*)ws + WS_GRP + (blk & 7) * 32;
  float* hbuf = ws + WS_HBUF;
  const uint4* wgt = (const uint4*)(ws + WS_WGT) + (size_t)blk * 384 * 8;

  // biases for this block's 4 units (combine wave w<4 uses u = blk*4 + wave)
  const int ub = __builtin_amdgcn_readfirstlane(blk * 4 + (wave & 3));
  const float bsf = bf[ub], bsi = bi[ub], bsc = bc[ub], bso = bo[ub];

  const float* rowy0 = Wfc + (size_t)(blk * 2 + 0) * HH;
  const float* rowy1 = Wfc + (size_t)(blk * 2 + 1) * HH;

  float cstate = 0.0f, hlast = 0.0f;     // valid on waves 0-3

  for (int it = 0; it <= TT; ++it) {
    const float* hprev = hbuf + (size_t)(it & 1) * (BB * HH);
    float*       hnext = hbuf + (size_t)((it + 1) & 1) * (BB * HH);
    const int xit = (it < TT) ? it : 0;

    float ag[4][4];
    #pragma unroll
    for (int u = 0; u < 4; ++u)
      #pragma unroll
      for (int g = 0; g < 4; ++g) ag[u][g] = 0.0f;
    float ay0 = 0.0f, ay1 = 0.0f;

    float4 vsA[2], vsB[2];
    ISSUE(vsA, 0); ISSUE(vsB, 1);        // x chunks: plain cached loads
    WRITE(vsA, 0);
    __syncthreads();

    #pragma unroll
    for (int kc = 0; kc < NCH; ++kc) {
      // issue chunk kc+2 early (c_j lives in vsA iff j even)
      if (kc + 2 < NCH) {
        if (kc & 1) { ISSUE(vsB, kc + 2); } else { ISSUE(vsA, kc + 2); }
      }

      // compute chunk kc: slots {2*wave, 2*wave+1}
      {
        const float4* cbf4 = (const float4*)(lds + ((kc & 1) ? L_COMB1 : L_COMB0));
        #pragma unroll
        for (int sl = 0; sl < 2; ++sl) {
          const int s  = 2 * wave + sl;
          const int sg = kc * NSL + s;
          float4 cv = cbf4[b * NSL + (s ^ mm)];
          if (it < TT) {
            h2 a01 = pkrtz(cv.x, cv.y);
            h2 a23 = pkrtz(cv.z, cv.w);
            const uint4* wv = wgt + (size_t)sg * 8;
            #pragma unroll
            for (int u = 0; u < 4; ++u) {
              uint4 q0 = wv[u*2+0];
              uint4 q1 = wv[u*2+1];
              ag[u][0] = FDOT2(a23, bc_h2(q0.y), FDOT2(a01, bc_h2(q0.x), ag[u][0]));
              ag[u][1] = FDOT2(a23, bc_h2(q0.w), FDOT2(a01, bc_h2(q0.z), ag[u][1]));
              ag[u][2] = FDOT2(a23, bc_h2(q1.y), FDOT2(a01, bc_h2(q1.x), ag[u][2]));
              ag[u][3] = FDOT2(a23, bc_h2(q1.w), FDOT2(a01, bc_h2(q1.z), ag[u][3]));
            }
          }
          if (kc >= 4 && it > 0) {       // y over h-part, fp32 (shares cv read)
            const int kh = sg * 4 - II;
            float4 wy0 = *(const float4*)(rowy0 + kh);
            float4 wy1 = *(const float4*)(rowy1 + kh);
            ay0 += cv.x*wy0.x + cv.y*wy0.y + cv.z*wy0.z + cv.w*wy0.w;
            ay1 += cv.x*wy1.x + cv.y*wy1.y + cv.z*wy1.z + cv.w*wy1.w;
          }
        }
      }

      if (kc + 1 < NCH) {
        if (kc & 1) { WRITE(vsA, kc + 1); } else { WRITE(vsB, kc + 1); }
        __syncthreads();
      }
    }

    // ---- publish partials ----
    if (it < TT) {
      #pragma unroll
      for (int u = 0; u < 4; ++u)
        #pragma unroll
        for (int g = 0; g < 4; ++g)
          lds[L_GPART + ((u*4 + g)*64 + b)*20 + wave] = ag[u][g];
    }
    if (it > 0) {
      lds[L_YBUF + wave*128 + 0*64 + b] = ay0;
      lds[L_YBUF + wave*128 + 1*64 + b] = ay1;
    }
    __syncthreads();

    // ---- gate combine + state update (waves 0-3; wave == ul) ----
    if (it < TT && wave < 4) {
      float t[4];
      #pragma unroll
      for (int g = 0; g < 4; ++g) {
        const float4* pp = (const float4*)(lds + L_GPART + ((wave*4 + g)*64 + b)*20);
        float4 p0 = pp[0], p1 = pp[1], p2 = pp[2], p3 = pp[3];
        t[g] = ((p0.x+p0.y)+(p0.z+p0.w)) + ((p1.x+p1.y)+(p1.z+p1.w))
             + ((p2.x+p2.y)+(p2.z+p2.w)) + ((p3.x+p3.y)+(p3.z+p3.w));
      }
      float gf = sigm(t[0] + bsf);
      float gi = sigm(t[1] + bsi);
      float gc = tanh_c(t[2] + bsc);
      float go = sigm(t[3] + bso);
      cstate = gf * cstate + gi * gc;
      float hv = go * tanh_c(cstate);
      hlast = hv;
      lds[L_HGATH + b*4 + wave] = hv;
    }

    // ---- y output for step it-1 (NT stores, no L2 allocation) ----
    if (it > 0 && tid < 2 * BB) {
      int q  = tid >> 6;
      int qb = tid & 63;
      float yv = bfc[blk*2 + q];
      #pragma unroll
      for (int w = 0; w < 16; ++w)
        yv += lds[L_YBUF + w*128 + q*64 + qb];
      __builtin_nontemporal_store(yv,
          &out[(size_t)qb * (TT*OO) + (size_t)(it-1) * OO + (blk*2 + q)]);
    }
    __syncthreads();

    // ---- coalesced h store: wave0, 2x 8B sc1 per lane ----
    if (it < TT && wave == 0) {
      float4 hq = *(const float4*)(lds + L_HGATH + b*4);
      float* hp = hnext + (size_t)b * HH + blk*4;
      cohere_st8(hp + 0, hq.x, hq.y);
      cohere_st8(hp + 2, hq.z, hq.w);
    }

    // ---- final h/c from registers ----
    if (it == TT && wave < 4) {
      out[(size_t)(BB*TT*OO) + (size_t)b * HH + (blk*4 + wave)] = hlast;
      out[(size_t)(BB*TT*OO + BB*HH) + (size_t)b * HH + (blk*4 + wave)] = cstate;
    }

    if (it < TT)
      grid_barrier(grpc, rootc, 32u * (uint32_t)(it + 1), 8u * (uint32_t)(it + 1));
  }
}

extern "C" void kernel_launch(void* const* d_in, const int* in_sizes, int n_in,
                              void* d_out, int out_size, void* d_ws, size_t ws_size,
                              hipStream_t stream) {
  (void)in_sizes; (void)n_in; (void)out_size; (void)ws_size;
  const float* x   = (const float*)d_in[0];
  const float* Wf  = (const float*)d_in[1];
  const float* bf  = (const float*)d_in[2];
  const float* Wi  = (const float*)d_in[3];
  const float* bi  = (const float*)d_in[4];
  const float* Wc  = (const float*)d_in[5];
  const float* bc  = (const float*)d_in[6];
  const float* Wo  = (const float*)d_in[7];
  const float* bo  = (const float*)d_in[8];
  const float* Wfc = (const float*)d_in[9];
  const float* bfc = (const float*)d_in[10];
  float* out = (float*)d_out;
  float* ws  = (float*)d_ws;

  // zero barrier counters + h0 (weights region rewritten by wprep each call)
  hipMemsetAsync(d_ws, 0, (size_t)WS_CTRL_FLOATS * sizeof(float), stream);

  // fp32 -> f16 interleaved weight pack
  wprep<<<dim3((NBLK*384 + 255)/256), dim3(256), 0, stream>>>(Wf, Wi, Wc, Wo, ws);

  hipFuncSetAttribute((const void*)lstm_kernel,
                      hipFuncAttributeMaxDynamicSharedMemorySize,
                      (int)(L_NFLOATS * sizeof(float)));

  void* args[] = { &x, &bf, &bi, &bc, &bo, &Wfc, &bfc, &out, &ws };
  hipLaunchCooperativeKernel(reinterpret_cast<void*>(lstm_kernel),
                             dim3(NBLK), dim3(NTHR), args,
                             (unsigned)(L_NFLOATS * sizeof(float)), stream);
}